// Round 13
// baseline (549.131 us; speedup 1.0000x reference)
//
#include <hip/hip_runtime.h>
#include <hip/hip_bf16.h>
#include <stdint.h>

#define Bb 32
#define Tt 2048
#define Dd 1024   // D_IN = D_H = D_OUT

typedef float    f32x4 __attribute__((ext_vector_type(4)));
typedef _Float16 f16x8 __attribute__((ext_vector_type(8)));
typedef uint32_t u32;

// ---- ws layout (bytes) ----
// 0        w2_ws  [32][1024] f32  (2 * s.W_a)          128K
// 131072   a_ws   [32][2048] f32                       256K
// 393216   UNION: e_part [4 obb][32 b][2048 t] f32 (1M, k_e->k_sm)
//                 cpart  [32 tc][32 b][1024] f32 (4M, k_c1->k_c2)
// 4587520  U_ts   tiled fp16 U^T (see k_ut)            2M
#define WS_A     131072
#define WS_EP    393216
#define WS_UT    4587520

__device__ __forceinline__ void gll16(const void* g, const void* lds) {
  __builtin_amdgcn_global_load_lds(
      (const __attribute__((address_space(1))) u32*)(uintptr_t)g,
      (__attribute__((address_space(3))) u32*)(uint32_t)(uintptr_t)lds,
      16, 0, 0);
}

// ---------------- kernel 1: w2[b][o] = 2 * sum_i s[b][i] * W[i][o] ----------------
__global__ __launch_bounds__(256) void k_ws(const float* __restrict__ s,
                                            const float* __restrict__ W,
                                            float* __restrict__ w2_ws) {
  const int b = blockIdx.x >> 2;
  const int o = (blockIdx.x & 3) * 256 + threadIdx.x;
  __shared__ float s_sh[Dd];
#pragma unroll
  for (int j = 0; j < 4; ++j)
    s_sh[threadIdx.x + 256 * j] = s[b * Dd + threadIdx.x + 256 * j];
  __syncthreads();
  float acc = 0.f;
#pragma unroll 8
  for (int i = 0; i < Dd; ++i) acc += s_sh[i] * W[(size_t)i * Dd + o];
  w2_ws[b * Dd + o] = 2.f * acc;
}

// ------- kernel 2: build U_ts, tile-major linear-lane layout (unchanged) -------
// Tile (ob 0..7, ks 0..15) = 16KB at (ob*16+ks)*16384; element (o_l, k_l):
// byte = (k_l>>5)*8192 + (o_l>>6)*4096 + ((o_l>>4)&3)*1024
//        + (((k_l>>3)&3)*16 + (o_l&15))*16 + (k_l&7)*2
__global__ __launch_bounds__(256) void k_ut(const float* __restrict__ U,
                                            uint8_t* __restrict__ U_ts) {
  const int i0 = (blockIdx.x >> 4) * 64;   // k-tile
  const int o0 = (blockIdx.x & 15) * 64;   // o-tile
  __shared__ float tile[64][65];           // [o_loc][k_loc]
  const int tx = threadIdx.x & 63;
  const int ty = threadIdx.x >> 6;
#pragma unroll
  for (int jj = 0; jj < 16; ++jj)
    tile[tx][ty + 4 * jj] = U[(size_t)(i0 + ty + 4 * jj) * Dd + o0 + tx];
  __syncthreads();
#pragma unroll
  for (int it = 0; it < 2; ++it) {
    const int g  = it * 256 + threadIdx.x;  // 0..511
    const int ol = g & 63;
    const int kg = g >> 6;                  // 0..7
    const int o  = o0 + ol;
    const int k  = i0 + kg * 8;
    f16x8 r;
#pragma unroll
    for (int m = 0; m < 8; ++m) r[m] = (_Float16)tile[ol][kg * 8 + m];
    const int ob  = o >> 7, ks = k >> 6;
    const int o_l = o & 127, k_l = k & 63;
    const size_t byte = ((size_t)(ob * 16 + ks) << 14)
                      + (size_t)((k_l >> 5) * 8192 + (o_l >> 6) * 4096
                      + ((o_l >> 4) & 3) * 1024
                      + (((k_l >> 3) & 3) * 16 + (o_l & 15)) * 16);
    *(f16x8*)(U_ts + byte) = r;
  }
}

// ---------------- kernel 3: fused GEMM, 128t x 256o, B direct-from-global ----------------
// 4 waves: hw = o-half(128), tw = t-half(64). Per wave 64t x 128o, acc[4][8],
// 64 MFMA/step (BK=64, 16 steps). A: gll16 double-buffer (2 x 32KB, only thing
// in LDS -> single barrier protects A only). B: per-lane f32 loads straight
// from h in fragment layout + in-reg cvt -> no ds_write/ds_read for B at all.
// Steady step: vmcnt(16) [A(ks) landed, B(ks)'s 16 loads newest]; barrier;
// stage A(ks+1); cvt bf<-br (reg-dep waits B(ks)); issue B(ks+1); 16 ds_read
// + 64 MFMA. Grid tb-fastest: 4 ob-sharers of an h-slice land on one XCD.
__global__ __launch_bounds__(256, 2) void k_e(const float* __restrict__ h,
                                              const uint8_t* __restrict__ U_ts,
                                              const float* __restrict__ w2_ws,
                                              const float* __restrict__ v_a,
                                              float* __restrict__ e_part) {
  const int blk = blockIdx.x;
  const int b   = blk >> 6;
  const int obb = (blk >> 4) & 3;   // 256-o block
  const int tb  = blk & 15;
  const int tid  = threadIdx.x;
  const int lane = tid & 63;
  const int w    = tid >> 6;
  const int hw   = w & 1;    // o-half (128)
  const int tw   = w >> 1;   // t-half (64)

  __shared__ __align__(16) uint8_t Al[2][32768];
  __shared__ float w_sh[256], v_sh[256], exch[128];

  // ---- prologue: w/v (drained before counting starts) ----
  w_sh[tid] = w2_ws[b * Dd + obb * 256 + tid];
  v_sh[tid] = v_a[obb * 256 + tid];
  asm volatile("s_waitcnt vmcnt(0)" ::: "memory");

  // A staging: 32 segs of 1KB per step; wave w stages segs w*8..w*8+7
  const int tile_i  = w >> 1;          // which 16KB half (o 0-127 / 128-255)
  const int segbase = (w & 1) * 8;
  const uint8_t* Usrc = U_ts + ((size_t)((2 * obb + tile_i) * 16) << 14)
                      + (size_t)segbase * 1024 + (size_t)lane * 16;
  uint8_t* Adst0 = &Al[0][tile_i * 16384 + segbase * 1024];
  uint8_t* Adst1 = &Al[1][tile_i * 16384 + segbase * 1024];

  // B addressing: lane reads h[t][k..k+7] with t = tb*128+tw*64+m*16+(lane&15),
  // k = ks*64 + kk*32 + (lane>>4)*8
  const float* hb = h + ((size_t)(b * Tt + tb * 128 + tw * 64 + (lane & 15))) * Dd
                  + (lane >> 4) * 8;

  f32x4 acc[4][8] = {};
  f32x4 br[16];   // B(ks) f32 staging (64 VGPR)
  f16x8 bf[8];    // cvt'd fragments [kk*4+m]

  // A(0), B(0)
  {
#pragma unroll
    for (int q = 0; q < 8; ++q) gll16(Usrc + q * 1024, Adst0 + q * 1024);
  }
#pragma unroll
  for (int kk = 0; kk < 2; ++kk)
#pragma unroll
    for (int m = 0; m < 4; ++m) {
      const float* p = hb + (size_t)m * 16 * Dd + kk * 32;
      br[kk * 8 + m * 2]     = *(const f32x4*)p;
      br[kk * 8 + m * 2 + 1] = *(const f32x4*)(p + 4);
    }
  asm volatile("s_waitcnt lgkmcnt(0)" ::: "memory");  // w_sh/v_sh visible

#pragma unroll 1
  for (int ks = 0; ks < 16; ++ks) {
    const int p = ks & 1;
    asm volatile("s_waitcnt vmcnt(16)" ::: "memory");  // A(ks) landed
    __builtin_amdgcn_sched_barrier(0);
    __builtin_amdgcn_s_barrier();
    __builtin_amdgcn_sched_barrier(0);
    if (ks < 15) {                      // stage A(ks+1) into other buffer
      const uint8_t* src = Usrc + ((size_t)(ks + 1) << 14);
      uint8_t* dst = p ? Adst0 : Adst1;
#pragma unroll
      for (int q = 0; q < 8; ++q) gll16(src + q * 1024, dst + q * 1024);
    }
    // cvt B(ks): register dependency makes compiler wait the right vmcnt
#pragma unroll
    for (int j = 0; j < 8; ++j) {
      f16x8 t;
#pragma unroll
      for (int m2 = 0; m2 < 4; ++m2) {
        t[m2]     = (_Float16)br[2 * j][m2];
        t[4 + m2] = (_Float16)br[2 * j + 1][m2];
      }
      bf[j] = t;
    }
    __builtin_amdgcn_sched_barrier(0);  // cvt before br overwrite
    if (ks < 15) {                      // issue B(ks+1) (stay in flight)
#pragma unroll
      for (int kk = 0; kk < 2; ++kk)
#pragma unroll
        for (int m = 0; m < 4; ++m) {
          const float* pp = hb + (size_t)m * 16 * Dd + (ks + 1) * 64 + kk * 32;
          br[kk * 8 + m * 2]     = *(const f32x4*)pp;
          br[kk * 8 + m * 2 + 1] = *(const f32x4*)(pp + 4);
        }
    }
    __builtin_amdgcn_sched_barrier(0);  // loads issued before MFMA block
    const uint8_t* Ab = &Al[p][hw * 16384] + lane * 16;
#pragma unroll
    for (int kk = 0; kk < 2; ++kk) {
      f16x8 af[8];
#pragma unroll
      for (int n = 0; n < 8; ++n)
        af[n] = *(const f16x8*)(Ab + kk * 8192 + (n >> 2) * 4096 + (n & 3) * 1024);
#pragma unroll
      for (int m = 0; m < 4; ++m)
#pragma unroll
        for (int n = 0; n < 8; ++n)
          acc[m][n] = __builtin_amdgcn_mfma_f32_16x16x32_f16(af[n], bf[kk * 4 + m],
                                                             acc[m][n], 0, 0, 0);
    }
  }

  // ---- epilogue: tanh + v-weight + reduce over o (256 per block) ----
  float ep[4] = {0.f, 0.f, 0.f, 0.f};
#pragma unroll
  for (int m = 0; m < 4; ++m)
#pragma unroll
    for (int n = 0; n < 8; ++n)
#pragma unroll
      for (int r = 0; r < 4; ++r) {
        const int o_loc = hw * 128 + n * 16 + ((lane >> 4) << 2) + r;
        const float x = __builtin_fmaf(acc[m][n][r], 2.f, w_sh[o_loc]);
        ep[m] += v_sh[o_loc] * (1.f - 2.f / (__expf(x) + 1.f));
      }
#pragma unroll
  for (int m = 0; m < 4; ++m) {
    ep[m] += __shfl_xor(ep[m], 16, 64);
    ep[m] += __shfl_xor(ep[m], 32, 64);
  }
  __syncthreads();
  if (hw == 1 && lane < 16) {
#pragma unroll
    for (int m = 0; m < 4; ++m) exch[tw * 64 + m * 16 + lane] = ep[m];
  }
  __syncthreads();
  if (hw == 0 && lane < 16) {
#pragma unroll
    for (int m = 0; m < 4; ++m) {
      const int t_loc = tw * 64 + m * 16 + lane;
      e_part[((size_t)(obb * Bb + b)) * Tt + tb * 128 + t_loc] = ep[m] + exch[t_loc];
    }
  }
}

// ---------------- kernel 4: reduce 4 o-partials + softmax over T per b ----------------
__global__ __launch_bounds__(256) void k_sm(const float* __restrict__ e_part,
                                            float* __restrict__ a_ws) {
  const int b = blockIdx.x;
  const int lane = threadIdx.x & 63;
  const int wv = threadIdx.x >> 6;
  __shared__ float red[8];
  float ev[8];
  float m = -1e30f;
#pragma unroll
  for (int j = 0; j < 8; ++j) {
    const int t = threadIdx.x + 256 * j;
    float sv = 0.f;
#pragma unroll
    for (int o = 0; o < 4; ++o) sv += e_part[((size_t)(o * Bb + b)) * Tt + t];
    ev[j] = sv;
    m = fmaxf(m, sv);
  }
#pragma unroll
  for (int sft = 1; sft < 64; sft <<= 1) m = fmaxf(m, __shfl_xor(m, sft, 64));
  if (lane == 0) red[wv] = m;
  __syncthreads();
  m = fmaxf(fmaxf(red[0], red[1]), fmaxf(red[2], red[3]));
  float sum = 0.f;
#pragma unroll
  for (int j = 0; j < 8; ++j) { ev[j] = __expf(ev[j] - m); sum += ev[j]; }
#pragma unroll
  for (int sft = 1; sft < 64; sft <<= 1) sum += __shfl_xor(sum, sft, 64);
  if (lane == 0) red[4 + wv] = sum;
  __syncthreads();
  const float inv = 1.f / (red[4] + red[5] + red[6] + red[7]);
#pragma unroll
  for (int j = 0; j < 8; ++j) a_ws[b * Tt + threadIdx.x + 256 * j] = ev[j] * inv;
}

// ---------------- kernel 5a: partial c over 64-t chunks (deterministic) ----------------
__global__ __launch_bounds__(256) void k_c1(const float* __restrict__ h,
                                            const float* __restrict__ a_ws,
                                            float* __restrict__ cpart) {
  const int b  = blockIdx.x >> 5;
  const int tc = blockIdx.x & 31;
  const int t0 = tc << 6;
  __shared__ float a_sh[64];
  if (threadIdx.x < 64) a_sh[threadIdx.x] = a_ws[b * Tt + t0 + threadIdx.x];
  __syncthreads();
  f32x4 acc = {0.f, 0.f, 0.f, 0.f};
  const float* hb = h + ((size_t)b * Tt + t0) * Dd + threadIdx.x * 4;
#pragma unroll 4
  for (int t = 0; t < 64; ++t) {
    const f32x4 hv = *(const f32x4*)(hb + (size_t)t * Dd);
    acc += a_sh[t] * hv;
  }
  *(f32x4*)(cpart + ((size_t)(tc * 32 + b) << 10) + threadIdx.x * 4) = acc;
}

// ---------------- kernel 5b: reduce partials, store f32 ----------------
__global__ __launch_bounds__(256) void k_c2(const float* __restrict__ cpart,
                                            float* __restrict__ out) {
  const int gid = blockIdx.x * 256 + threadIdx.x;   // 0..32767
  const int b = gid >> 10;
  const int d = gid & 1023;
  float sv = 0.f;
#pragma unroll
  for (int tc = 0; tc < 32; ++tc) sv += cpart[((size_t)(tc * 32 + b) << 10) + d];
  out[gid] = sv;
}

extern "C" void kernel_launch(void* const* d_in, const int* in_sizes, int n_in,
                              void* d_out, int out_size, void* d_ws, size_t ws_size,
                              hipStream_t stream) {
  (void)in_sizes; (void)n_in; (void)out_size; (void)ws_size;
  const float* s  = (const float*)d_in[0];
  const float* h  = (const float*)d_in[1];
  const float* W  = (const float*)d_in[2];
  const float* U  = (const float*)d_in[3];
  const float* v  = (const float*)d_in[4];
  uint8_t* ws = (uint8_t*)d_ws;
  float*   w2_ws  = (float*)ws;
  float*   a_ws   = (float*)(ws + WS_A);
  float*   e_part = (float*)(ws + WS_EP);   // aliases cpart (sequential lifetimes)
  float*   cpart  = (float*)(ws + WS_EP);
  uint8_t* U_ts   = ws + WS_UT;

  k_ws<<<128, 256, 0, stream>>>(s, W, w2_ws);
  k_ut<<<256, 256, 0, stream>>>(U, U_ts);
  k_e <<<2048, 256, 0, stream>>>(h, U_ts, w2_ws, v, e_part);
  k_sm<<<Bb, 256, 0, stream>>>(e_part, a_ws);
  k_c1<<<1024, 256, 0, stream>>>(h, a_ws, cpart);
  k_c2<<<128, 256, 0, stream>>>(cpart, (float*)d_out);
}